// Round 4
// baseline (183.100 us; speedup 1.0000x reference)
//
#include <hip/hip_runtime.h>

#define RADIUS 8
#define N 512
#define TR 32                  // output rows per block strip
#define LSTRIDE (N + 2)        // 514: keeps 8B alignment for float2 LDS ops;
                               // 514%32=2 → worst 4-way aliasing, ~µs-level cost

__global__ __launch_bounds__(512, 4)
void box_kernel(const float* __restrict__ in, float* __restrict__ out) {
    __shared__ float tile[TR * LSTRIDE];   // 32*514*4 = 64.25 KiB → 2 blocks/CU

    const int blk   = blockIdx.x;
    const int img   = blk >> 4;            // 16 strips per 512-row image
    const int strip = blk & 15;
    const int r0    = strip * TR;
    const float* __restrict__ ibase = in  + (size_t)img * N * N;
    float* __restrict__       obase = out + (size_t)img * N * N;
    const int t = threadIdx.x;

    // ---- Phase 1: vertical 17-tap sliding sum. 256 threads own 2 columns each
    // (float2 loads, 8 B/lane → half the global request count of scalar).
    // 17-deep register ring keeps live set ~40 VGPRs → no spill at the 64 cap.
    if (t < 256) {
        const int c2 = t * 2;
        float2 ring[17];                   // static %17 indices after full unroll
        float sx = 0.0f, sy = 0.0f;
#pragma unroll
        for (int k = 0; k < TR + 2 * RADIUS; ++k) {
            const int row = r0 + k - RADIUS;
            float2 v = make_float2(0.0f, 0.0f);
            if (row >= 0 && row < N)
                v = *reinterpret_cast<const float2*>(ibase + (size_t)row * N + c2);
            sx += v.x; sy += v.y;
            if (k >= 17) { sx -= ring[k % 17].x; sy -= ring[k % 17].y; }
            ring[k % 17] = v;
            if (k >= 2 * RADIUS) {         // window rows complete for output row k-16
                const int i = k - 2 * RADIUS;
                *reinterpret_cast<float2*>(&tile[i * LSTRIDE + c2]) =
                    make_float2(sx, sy);
            }
        }
    }
    __syncthreads();

    // ---- Phase 2: horizontal 17-tap sliding sum + direct vectored stores.
    // thread → (row, 32-col segment); h[4] staging → float4 store every 4 cols;
    // each thread's 8 stores complete one full 128B line per row (L2 merges).
    const int hrow = t & (TR - 1);
    const int seg  = t >> 5;
    const int c0   = seg * 32;
    const float* trow = &tile[hrow * LSTRIDE];
    float hs = 0.0f;
#pragma unroll
    for (int k = -RADIUS; k <= RADIUS; ++k) {
        const int col = c0 + k;
        if (col >= 0 && col < N) hs += trow[col];
    }
    float* orow = obase + (size_t)(r0 + hrow) * N;
    float h[4];
#pragma unroll
    for (int j = 0; j < 32; ++j) {
        h[j & 3] = hs;
        const int ac = c0 + j + 1 + RADIUS;
        const int sc = c0 + j - RADIUS;
        const float a  = (ac < N) ? trow[ac] : 0.0f;
        const float sb = (sc >= 0) ? trow[sc] : 0.0f;
        hs += a - sb;
        if ((j & 3) == 3) {
            *reinterpret_cast<float4*>(orow + c0 + j - 3) =
                make_float4(h[0], h[1], h[2], h[3]);
        }
    }
}

extern "C" void kernel_launch(void* const* d_in, const int* in_sizes, int n_in,
                              void* d_out, int out_size, void* d_ws, size_t ws_size,
                              hipStream_t stream) {
    const float* in = (const float*)d_in[0];
    float* out = (float*)d_out;
    dim3 grid(8 * 32 * (N / TR));          // 4096 blocks
    dim3 block(512);
    hipLaunchKernelGGL(box_kernel, grid, block, 0, stream, in, out);
}

// Round 5
// 119.083 us; speedup vs baseline: 1.5376x; 1.5376x over previous
//
#include <hip/hip_runtime.h>

#define RADIUS 8
#define N 512
#define TR 32                   // output rows per block strip
#define LSTRIDE 516             // dwords; %4==0 → 16B-aligned float4 rows; 516%32=4 → P1 writes 2-way (free)

__global__ __launch_bounds__(512, 4)
void box_kernel(const float* __restrict__ in, float* __restrict__ out) {
    __shared__ __align__(16) float tile[TR * LSTRIDE];   // 66,048 B → 2 blocks/CU

    const int blk   = blockIdx.x;
    const int img   = blk >> 4;           // 16 strips per 512-row image
    const int strip = blk & 15;
    const int r0    = strip * TR;
    const float* __restrict__ ibase = in  + (size_t)img * N * N;
    float* __restrict__       obase = out + (size_t)img * N * N;
    const int t = threadIdx.x;

    // ---- Phase 1: vertical 17-tap sliding sum, thread-per-column (coalesced
    // scalar loads), 16-deep register ring (static k&15 indices -> no scratch).
    {
        const int c = t;
        float ring[16];
        float vs = 0.0f;
#pragma unroll
        for (int k = 0; k < TR + 2 * RADIUS; ++k) {
            const int row = r0 + k - RADIUS;
            float v = 0.0f;
            if (row >= 0 && row < N) v = ibase[(size_t)row * N + c];
            vs += v;
            if (k >= 2 * RADIUS) {                    // output row i = k-16 complete
                tile[(k - 2 * RADIUS) * LSTRIDE + c] = vs;
                vs -= ring[k & 15];                   // drop row loaded 16 steps ago
            }
            ring[k & 15] = v;
        }
    }
    __syncthreads();

    // ---- Phase 2: horizontal 17-tap sum, thread = (row-group, col-quad).
    // Reads: 5 aligned ds_read_b128 per row (conflict-free: 8-lane groups hit
    // banks 0,4..28). Stores: wave = 64 consecutive quads on ONE row -> 1KB
    // contiguous float4 store, full 128B lines, no write amplification.
    const int qid  = t & 127;             // col-quad 0..127 -> cols qid*4..+3
    const int rgrp = t >> 7;              // 0..3 -> rows rgrp*8..+7
    const int q0   = qid * 4;
#pragma unroll
    for (int i = 0; i < 8; ++i) {
        const int r = rgrp * 8 + i;
        const float* trow = &tile[r * LSTRIDE];
        float wv[20];                     // window cols q0-8 .. q0+11
#pragma unroll
        for (int p = 0; p < 5; ++p) {
            const int cs = q0 - 8 + 4 * p;            // ≡0 mod 4; blocks fully in or out
            float4 vv = (cs >= 0 && cs < N)
                      ? *reinterpret_cast<const float4*>(trow + cs)
                      : make_float4(0.0f, 0.0f, 0.0f, 0.0f);
            wv[4 * p + 0] = vv.x; wv[4 * p + 1] = vv.y;
            wv[4 * p + 2] = vv.z; wv[4 * p + 3] = vv.w;
        }
        float s = 0.0f;
#pragma unroll
        for (int k = 0; k < 17; ++k) s += wv[k];      // out col q0: wv[0..16]
        const float o0 = s;
        const float o1 = o0 - wv[0] + wv[17];
        const float o2 = o1 - wv[1] + wv[18];
        const float o3 = o2 - wv[2] + wv[19];
        *reinterpret_cast<float4*>(obase + (size_t)(r0 + r) * N + q0) =
            make_float4(o0, o1, o2, o3);
    }
}

extern "C" void kernel_launch(void* const* d_in, const int* in_sizes, int n_in,
                              void* d_out, int out_size, void* d_ws, size_t ws_size,
                              hipStream_t stream) {
    const float* in = (const float*)d_in[0];
    float* out = (float*)d_out;
    dim3 grid(8 * 32 * (N / TR));          // 4096 blocks
    dim3 block(512);
    hipLaunchKernelGGL(box_kernel, grid, block, 0, stream, in, out);
}

// Round 6
// 108.121 us; speedup vs baseline: 1.6935x; 1.1014x over previous
//
#include <hip/hip_runtime.h>

#define RADIUS 8
#define N 512
#define TR 32                   // output rows per block strip
#define LSTRIDE 516             // dwords; %4==0 → 16B-aligned rows for b128; P1 writes conflict-free

__global__ __launch_bounds__(512, 4)
void box_kernel(const float* __restrict__ in, float* __restrict__ out) {
    __shared__ __align__(16) float tile[TR * LSTRIDE];   // 66,048 B → 2 blocks/CU

    const int blk   = blockIdx.x;
    const int img   = blk >> 4;           // 16 strips per 512-row image
    const int strip = blk & 15;
    const int r0    = strip * TR;
    const float* __restrict__ ibase = in  + (size_t)img * N * N;
    float* __restrict__       obase = out + (size_t)img * N * N;
    const int t = threadIdx.x;

    // ---- Phase 1 (R1 structure, unchanged): burst-load ALL 48 window rows
    // into registers FIRST — 48 independent outstanding loads/wave is the MLP
    // that sustains HBM BW — then vertical 17-tap sliding sum into LDS.
    {
        const int c = t;                  // column 0..511
        float x[48];
#pragma unroll
        for (int k = 0; k < 48; ++k) {
            const int row = r0 + k - RADIUS;
            x[k] = (row >= 0 && row < N) ? ibase[(size_t)row * N + c] : 0.0f;
        }
        float vs = 0.0f;
#pragma unroll
        for (int k = 0; k <= 2 * RADIUS; ++k) vs += x[k];
#pragma unroll
        for (int i = 0; i < TR; ++i) {
            tile[i * LSTRIDE + c] = vs;   // consecutive dwords → conflict-free
            if (i + 1 < TR) vs += x[i + 2 * RADIUS + 1] - x[i];
        }
    }
    __syncthreads();

    // ---- Phase 2 (R5 structure): thread = (row-group, col-quad).
    // Reads: 5 aligned ds_read_b128 per row (minimum-aliasing wrap of 32 banks).
    // Stores: wave = 64 consecutive quads on ONE row → 1 KB contiguous float4
    // store, full 128 B lines, no write amplification. No phase 3, no more barriers.
    const int qid  = t & 127;             // col-quad 0..127 → cols qid*4..+3
    const int rgrp = t >> 7;              // 0..3 → rows rgrp*8..+7
    const int q0   = qid * 4;
#pragma unroll
    for (int i = 0; i < 8; ++i) {
        const int r = rgrp * 8 + i;
        const float* trow = &tile[r * LSTRIDE];
        float wv[20];                     // window cols q0-8 .. q0+11 (OOB → 0)
#pragma unroll
        for (int p = 0; p < 5; ++p) {
            const int cs = q0 - 8 + 4 * p;            // ≡ 0 mod 4; quad fully in or out
            float4 vv = (cs >= 0 && cs < N)
                      ? *reinterpret_cast<const float4*>(trow + cs)
                      : make_float4(0.0f, 0.0f, 0.0f, 0.0f);
            wv[4 * p + 0] = vv.x; wv[4 * p + 1] = vv.y;
            wv[4 * p + 2] = vv.z; wv[4 * p + 3] = vv.w;
        }
        float s = 0.0f;
#pragma unroll
        for (int k = 0; k < 17; ++k) s += wv[k];      // out col q0: wv[0..16]
        const float o0 = s;
        const float o1 = o0 - wv[0] + wv[17];
        const float o2 = o1 - wv[1] + wv[18];
        const float o3 = o2 - wv[2] + wv[19];
        *reinterpret_cast<float4*>(obase + (size_t)(r0 + r) * N + q0) =
            make_float4(o0, o1, o2, o3);
    }
}

extern "C" void kernel_launch(void* const* d_in, const int* in_sizes, int n_in,
                              void* d_out, int out_size, void* d_ws, size_t ws_size,
                              hipStream_t stream) {
    const float* in = (const float*)d_in[0];
    float* out = (float*)d_out;
    dim3 grid(8 * 32 * (N / TR));          // 4096 blocks
    dim3 block(512);
    hipLaunchKernelGGL(box_kernel, grid, block, 0, stream, in, out);
}